// Round 1
// baseline (127.441 us; speedup 1.0000x reference)
//
#include <hip/hip_runtime.h>
#include <math.h>

// Problem constants
#define NB    64     // batch
#define L0    128    // input length
#define C0    16     // input channels
#define KW    5      // conv kernel size
#define NF    8      // filters per group
// Block1: 128 out ch, L=124 ; Block2: 1024 out ch, L=120 ; Block3: 8192 out ch, L=116
#define L1    124
#define L2    120
#define L3    116
#define CH1   128
#define CH2   1024
#define CH3   8192
#define NCHUNK 8     // channel chunks: each owns 2 state ch -> 16 y1 ch -> 128 y2 ch -> 1024 y3 ch

// ---------------------------------------------------------------------------
// Kernel A: fused block1 + block2 for one (chunk, batch).
// Writes y2 [b][t2][ch2] (channel-contiguous) to workspace.
// ---------------------------------------------------------------------------
__global__ __launch_bounds__(256) void conv12_kernel(
    const float* __restrict__ state,   // [64][128][16]
    const float* __restrict__ k1,      // [5][1][128]
    const float* __restrict__ b1,      // [128]
    const float* __restrict__ k2,      // [5][1][1024]
    const float* __restrict__ b2,      // [1024]
    float* __restrict__ y2)            // [64][120][1024]
{
    const int chunk = blockIdx.x;      // 0..7
    const int b     = blockIdx.y;      // 0..63
    const int tid   = threadIdx.x;

    __shared__ float s_state[L0][2];   // 2 state channels for this chunk
    __shared__ float s_y1[L1][16];     // 16 y1 channels for this chunk

    // stage state: 128 rows x 2 channels = 256 values
    {
        int l = tid >> 1, c = tid & 1;
        s_state[l][c] = state[(size_t)b * L0 * C0 + l * C0 + chunk * 2 + c];
    }
    __syncthreads();

    // block1: y1[t1][jloc], j = chunk*16 + jloc, state channel = jloc/8
    for (int idx = tid; idx < L1 * 16; idx += 256) {
        int t1 = idx >> 4, jloc = idx & 15;
        int j = chunk * 16 + jloc;
        int cloc = jloc >> 3;
        float acc = b1[j];
#pragma unroll
        for (int k = 0; k < KW; ++k)
            acc = fmaf(s_state[t1 + k][cloc], k1[k * CH1 + j], acc);
        s_y1[t1][jloc] = fmaxf(acc, 0.f);
    }
    __syncthreads();

    // block2: y2[t2][m], m = chunk*128 + mloc, y1 channel = mloc/8
    float* y2b = y2 + (size_t)b * L2 * CH2 + chunk * 128;
    for (int idx = tid; idx < L2 * 128; idx += 256) {
        int t2 = idx >> 7, mloc = idx & 127;
        int m = chunk * 128 + mloc;
        int jloc = mloc >> 3;
        float acc = b2[m];
#pragma unroll
        for (int k = 0; k < KW; ++k)
            acc = fmaf(s_y1[t2 + k][jloc], k2[k * CH2 + m], acc);
        y2b[(size_t)t2 * CH2 + mloc] = fmaxf(acc, 0.f);
    }
}

// ---------------------------------------------------------------------------
// Kernel B: fused block3 + dense partial-dot for one (chunk, batch).
// Thread tid owns y2 channel c3 = chunk*128 + tid (-> 8 output channels).
// W rows t3*8192 + c3*8 + f, 2 cols -> 16 contiguous floats per (t3, thread):
// loaded as 4x float4, perfectly coalesced across the wave.
// Writes partials[b][chunk][2] (deterministic, no atomics).
// ---------------------------------------------------------------------------
__global__ __launch_bounds__(128) void conv3_dense_kernel(
    const float* __restrict__ y2,      // [64][120][1024]
    const float* __restrict__ k3,      // [5][1][8192]
    const float* __restrict__ b3,      // [8192]
    const float* __restrict__ W,       // [950272][2]
    float* __restrict__ partials)      // [64][8][2]
{
    const int chunk = blockIdx.x;      // 0..7
    const int b     = blockIdx.y;      // 0..63
    const int tid   = threadIdx.x;     // 0..127
    const int c3    = chunk * 128 + tid;

    __shared__ float tile[L2][128];    // y2 slice for this chunk: 61.4 KB

    // stage y2 tile (coalesced: 128 consecutive channels per row)
    const float* y2b = y2 + (size_t)b * L2 * CH2 + chunk * 128;
    for (int t = 0; t < L2; ++t)
        tile[t][tid] = y2b[(size_t)t * CH2 + tid];

    // per-thread conv3 weights + bias (register-resident)
    float kw[KW][NF], bv[NF];
#pragma unroll
    for (int k = 0; k < KW; ++k)
#pragma unroll
        for (int f = 0; f < NF; ++f)
            kw[k][f] = k3[k * CH3 + c3 * NF + f];
#pragma unroll
    for (int f = 0; f < NF; ++f)
        bv[f] = b3[c3 * NF + f];

    __syncthreads();

    // 4 accumulator pairs to shorten the serial FMA chain
    float a0x = 0.f, a0y = 0.f, a1x = 0.f, a1y = 0.f;
    float a2x = 0.f, a2y = 0.f, a3x = 0.f, a3y = 0.f;

    const float4* __restrict__ W4 = (const float4*)W;

    for (int t3 = 0; t3 < L3; ++t3) {
        float w0 = tile[t3 + 0][tid];
        float w1 = tile[t3 + 1][tid];
        float w2 = tile[t3 + 2][tid];
        float w3 = tile[t3 + 3][tid];
        float w4 = tile[t3 + 4][tid];

        float v[NF];
#pragma unroll
        for (int f = 0; f < NF; ++f) {
            float a = bv[f];
            a = fmaf(w0, kw[0][f], a);
            a = fmaf(w1, kw[1][f], a);
            a = fmaf(w2, kw[2][f], a);
            a = fmaf(w3, kw[3][f], a);
            a = fmaf(w4, kw[4][f], a);
            v[f] = fmaxf(a, 0.f);
        }

        // W float4 base: ((t3*8192 + c3*8) * 2) / 4 = t3*4096 + c3*4
        size_t base4 = (size_t)t3 * 4096 + (size_t)c3 * 4;
        float4 q0 = W4[base4 + 0];
        float4 q1 = W4[base4 + 1];
        float4 q2 = W4[base4 + 2];
        float4 q3 = W4[base4 + 3];

        a0x = fmaf(v[0], q0.x, a0x); a0y = fmaf(v[0], q0.y, a0y);
        a0x = fmaf(v[1], q0.z, a0x); a0y = fmaf(v[1], q0.w, a0y);
        a1x = fmaf(v[2], q1.x, a1x); a1y = fmaf(v[2], q1.y, a1y);
        a1x = fmaf(v[3], q1.z, a1x); a1y = fmaf(v[3], q1.w, a1y);
        a2x = fmaf(v[4], q2.x, a2x); a2y = fmaf(v[4], q2.y, a2y);
        a2x = fmaf(v[5], q2.z, a2x); a2y = fmaf(v[5], q2.w, a2y);
        a3x = fmaf(v[6], q3.x, a3x); a3y = fmaf(v[6], q3.y, a3y);
        a3x = fmaf(v[7], q3.z, a3x); a3y = fmaf(v[7], q3.w, a3y);
    }

    float acc0 = (a0x + a1x) + (a2x + a3x);
    float acc1 = (a0y + a1y) + (a2y + a3y);

    // wave (64-lane) reduction, then cross-wave combine in LDS
#pragma unroll
    for (int d = 32; d >= 1; d >>= 1) {
        acc0 += __shfl_down(acc0, d, 64);
        acc1 += __shfl_down(acc1, d, 64);
    }
    __shared__ float red[2][2];
    int wave = tid >> 6, lane = tid & 63;
    if (lane == 0) { red[wave][0] = acc0; red[wave][1] = acc1; }
    __syncthreads();
    if (tid == 0) {
        partials[((size_t)b * NCHUNK + chunk) * 2 + 0] = red[0][0] + red[1][0];
        partials[((size_t)b * NCHUNK + chunk) * 2 + 1] = red[0][1] + red[1][1];
    }
}

// ---------------------------------------------------------------------------
// Kernel C: combine 8 chunk-partials per (b, a), add dense bias, tanh.
// ---------------------------------------------------------------------------
__global__ __launch_bounds__(128) void finish_kernel(
    const float* __restrict__ partials,  // [64][8][2]
    const float* __restrict__ bd,        // [2]
    float* __restrict__ out)             // [64][2]
{
    int i = threadIdx.x;                 // 0..127
    int b = i >> 1, a = i & 1;
    float s = bd[a];
#pragma unroll
    for (int p = 0; p < NCHUNK; ++p)
        s += partials[((size_t)b * NCHUNK + p) * 2 + a];
    out[b * 2 + a] = tanhf(s);
}

extern "C" void kernel_launch(void* const* d_in, const int* in_sizes, int n_in,
                              void* d_out, int out_size, void* d_ws, size_t ws_size,
                              hipStream_t stream) {
    const float* state = (const float*)d_in[0];
    const float* k1    = (const float*)d_in[1];
    const float* b1    = (const float*)d_in[2];
    const float* k2    = (const float*)d_in[3];
    const float* b2    = (const float*)d_in[4];
    const float* k3    = (const float*)d_in[5];
    const float* b3    = (const float*)d_in[6];
    const float* W     = (const float*)d_in[7];
    const float* bd    = (const float*)d_in[8];
    float* out = (float*)d_out;

    float* y2       = (float*)d_ws;                 // 64*120*1024 fp32 = 31.5 MB
    float* partials = y2 + (size_t)NB * L2 * CH2;   // 64*8*2 fp32

    dim3 gridA(NCHUNK, NB);
    conv12_kernel<<<gridA, 256, 0, stream>>>(state, k1, b1, k2, b2, y2);

    dim3 gridB(NCHUNK, NB);
    conv3_dense_kernel<<<gridB, 128, 0, stream>>>(y2, k3, b3, W, partials);

    finish_kernel<<<1, 128, 0, stream>>>(partials, bd, out);
}

// Round 2
// 105.252 us; speedup vs baseline: 1.2108x; 1.2108x over previous
//
#include <hip/hip_runtime.h>
#include <math.h>

// Problem constants
#define NB    64     // batch
#define L0    128    // input length
#define C0    16     // input channels
#define KW    5      // conv kernel size
#define NF    8      // filters per group
#define L1    124
#define L2    120
#define L3    116
#define CH1   128
#define CH2   1024
#define CH3   8192
#define NCHUNK 8     // channel chunks: 2 state ch -> 16 y1 ch -> 128 y2 ch -> 1024 y3 ch
#define NS     4     // time slices of block-3 output
#define SLICE  29    // L3 / NS
#define TROWS  (SLICE + 4)    // y2 rows needed per slice   = 33
#define Y1R    (SLICE + 8)    // y1 rows needed per slice   = 37
#define STR    (SLICE + 12)   // state rows needed per slice = 41

// ---------------------------------------------------------------------------
// Fully fused kernel: conv1+conv2 (staged in LDS) + conv3 + dense partial dot.
// Grid: (chunk=8, b=64, slice=4). Block: 128 threads, thread tid owns y2
// channel c3 = chunk*128 + tid (-> 8 conv3 outputs -> 16 W elements per t3).
// blockIdx.x = chunk keeps each chunk's 950 KB W-slice resident in one XCD L2.
// ---------------------------------------------------------------------------
__global__ __launch_bounds__(128, 4) void actor_fused_kernel(
    const float* __restrict__ state,   // [64][128][16]
    const float* __restrict__ k1,      // [5][1][128]
    const float* __restrict__ b1,      // [128]
    const float* __restrict__ k2,      // [5][1][1024]
    const float* __restrict__ b2,      // [1024]
    const float* __restrict__ k3,      // [5][1][8192]
    const float* __restrict__ b3,      // [8192]
    const float* __restrict__ W,       // [950272][2]
    float* __restrict__ partials)      // [64][8][4][2]
{
    const int chunk = blockIdx.x;      // 0..7
    const int b     = blockIdx.y;      // 0..63
    const int slice = blockIdx.z;      // 0..3
    const int t0    = slice * SLICE;   // global t3 offset
    const int tid   = threadIdx.x;     // 0..127
    const int c3    = chunk * 128 + tid;

    __shared__ float s_state[STR][2];   // 41 x 2  (328 B)
    __shared__ float s_y1[Y1R][16];     // 37 x 16 (2.4 KB)
    __shared__ float tile[TROWS][128];  // 33 x 128 (16.9 KB) — y2 slice

    // ---- stage state rows [t0, t0+41), this chunk's 2 channels ----
    for (int idx = tid; idx < STR * 2; idx += 128) {
        int r = idx >> 1, c = idx & 1;
        s_state[r][c] = state[(size_t)b * L0 * C0 + (t0 + r) * C0 + chunk * 2 + c];
    }
    __syncthreads();

    // ---- block1: y1 rows [t0, t0+37), 16 channels of this chunk ----
    for (int idx = tid; idx < Y1R * 16; idx += 128) {
        int r = idx >> 4, jloc = idx & 15;
        int j = chunk * 16 + jloc;
        int cloc = jloc >> 3;
        float acc = b1[j];
#pragma unroll
        for (int k = 0; k < KW; ++k)
            acc = fmaf(s_state[r + k][cloc], k1[k * CH1 + j], acc);
        s_y1[r][jloc] = fmaxf(acc, 0.f);
    }
    __syncthreads();

    // ---- block2: y2 rows [t0, t0+33) for channel tid (own column only) ----
    {
        int m = chunk * 128 + tid;
        int jloc = tid >> 3;
        float kk[KW], bb = b2[m];
#pragma unroll
        for (int k = 0; k < KW; ++k) kk[k] = k2[k * CH2 + m];
        for (int r = 0; r < TROWS; ++r) {
            float acc = bb;
#pragma unroll
            for (int k = 0; k < KW; ++k)
                acc = fmaf(s_y1[r + k][jloc], kk[k], acc);
            tile[r][tid] = fmaxf(acc, 0.f);
        }
        // NOTE: no barrier needed — each thread reads only its own column below.
    }

    // ---- conv3 weights + bias (register-resident) ----
    float kw[KW][NF], bv[NF];
#pragma unroll
    for (int k = 0; k < KW; ++k)
#pragma unroll
        for (int f = 0; f < NF; ++f)
            kw[k][f] = k3[k * CH3 + c3 * NF + f];
#pragma unroll
    for (int f = 0; f < NF; ++f)
        bv[f] = b3[c3 * NF + f];

    // ---- main loop: conv3 + relu + dense partial dot ----
    float a0x = 0.f, a0y = 0.f, a1x = 0.f, a1y = 0.f;
    float a2x = 0.f, a2y = 0.f, a3x = 0.f, a3y = 0.f;

    const float4* __restrict__ W4 = (const float4*)W;

    // rolling 5-row window of own y2 column
    float w0 = tile[0][tid];
    float w1 = tile[1][tid];
    float w2 = tile[2][tid];
    float w3 = tile[3][tid];

    for (int t = 0; t < SLICE; ++t) {
        float w4 = tile[t + 4][tid];

        float v[NF];
#pragma unroll
        for (int f = 0; f < NF; ++f) {
            float a = bv[f];
            a = fmaf(w0, kw[0][f], a);
            a = fmaf(w1, kw[1][f], a);
            a = fmaf(w2, kw[2][f], a);
            a = fmaf(w3, kw[3][f], a);
            a = fmaf(w4, kw[4][f], a);
            v[f] = fmaxf(a, 0.f);
        }

        // W float4 base: ((t3*8192 + c3*8) * 2) / 4 = t3*4096 + c3*4
        size_t base4 = (size_t)(t0 + t) * 4096 + (size_t)c3 * 4;
        float4 q0 = W4[base4 + 0];
        float4 q1 = W4[base4 + 1];
        float4 q2 = W4[base4 + 2];
        float4 q3 = W4[base4 + 3];

        a0x = fmaf(v[0], q0.x, a0x); a0y = fmaf(v[0], q0.y, a0y);
        a0x = fmaf(v[1], q0.z, a0x); a0y = fmaf(v[1], q0.w, a0y);
        a1x = fmaf(v[2], q1.x, a1x); a1y = fmaf(v[2], q1.y, a1y);
        a1x = fmaf(v[3], q1.z, a1x); a1y = fmaf(v[3], q1.w, a1y);
        a2x = fmaf(v[4], q2.x, a2x); a2y = fmaf(v[4], q2.y, a2y);
        a2x = fmaf(v[5], q2.z, a2x); a2y = fmaf(v[5], q2.w, a2y);
        a3x = fmaf(v[6], q3.x, a3x); a3y = fmaf(v[6], q3.y, a3y);
        a3x = fmaf(v[7], q3.z, a3x); a3y = fmaf(v[7], q3.w, a3y);

        w0 = w1; w1 = w2; w2 = w3; w3 = w4;
    }

    float acc0 = (a0x + a1x) + (a2x + a3x);
    float acc1 = (a0y + a1y) + (a2y + a3y);

    // wave (64-lane) butterfly reduction, then cross-wave combine
#pragma unroll
    for (int d = 32; d >= 1; d >>= 1) {
        acc0 += __shfl_down(acc0, d, 64);
        acc1 += __shfl_down(acc1, d, 64);
    }
    __shared__ float red[2][2];
    int wave = tid >> 6, lane = tid & 63;
    if (lane == 0) { red[wave][0] = acc0; red[wave][1] = acc1; }
    __syncthreads();
    if (tid == 0) {
        size_t o = (((size_t)b * NCHUNK + chunk) * NS + slice) * 2;
        partials[o + 0] = red[0][0] + red[1][0];
        partials[o + 1] = red[0][1] + red[1][1];
    }
}

// ---------------------------------------------------------------------------
// Combine 32 partials per (b, a), add dense bias, tanh.
// ---------------------------------------------------------------------------
__global__ __launch_bounds__(128) void finish_kernel(
    const float* __restrict__ partials,  // [64][8][4][2] = [64][32][2]
    const float* __restrict__ bd,        // [2]
    float* __restrict__ out)             // [64][2]
{
    int i = threadIdx.x;                 // 0..127
    int b = i >> 1, a = i & 1;
    float s = bd[a];
#pragma unroll
    for (int p = 0; p < NCHUNK * NS; ++p)
        s += partials[((size_t)b * NCHUNK * NS + p) * 2 + a];
    out[b * 2 + a] = tanhf(s);
}

extern "C" void kernel_launch(void* const* d_in, const int* in_sizes, int n_in,
                              void* d_out, int out_size, void* d_ws, size_t ws_size,
                              hipStream_t stream) {
    const float* state = (const float*)d_in[0];
    const float* k1    = (const float*)d_in[1];
    const float* b1    = (const float*)d_in[2];
    const float* k2    = (const float*)d_in[3];
    const float* b2    = (const float*)d_in[4];
    const float* k3    = (const float*)d_in[5];
    const float* b3    = (const float*)d_in[6];
    const float* W     = (const float*)d_in[7];
    const float* bd    = (const float*)d_in[8];
    float* out = (float*)d_out;

    float* partials = (float*)d_ws;   // 64*8*4*2 fp32 = 16 KB

    dim3 grid(NCHUNK, NB, NS);
    actor_fused_kernel<<<grid, 128, 0, stream>>>(
        state, k1, b1, k2, b2, k3, b3, W, partials);

    finish_kernel<<<1, 128, 0, stream>>>(partials, bd, out);
}

// Round 3
// 98.384 us; speedup vs baseline: 1.2953x; 1.0698x over previous
//
#include <hip/hip_runtime.h>
#include <math.h>

// Problem constants
#define NB    64     // batch
#define L0    128    // input length
#define C0    16     // input channels
#define KW    5      // conv kernel size
#define NF    8      // filters per group
#define L1    124
#define L2    120
#define L3    116
#define CH1   128
#define CH2   1024
#define CH3   8192
#define NCHUNK 8     // channel chunks: 2 state ch -> 16 y1 ch -> 128 y2 ch -> 1024 y3 ch
#define NS     4     // time slices of block-3 output
#define SLICE  29    // L3 / NS
#define TROWS  (SLICE + 4)    // y2 rows needed per slice    = 33
#define Y1R    (SLICE + 8)    // y1 rows needed per slice    = 37
#define STR    (SLICE + 12)   // state rows needed per slice = 41
#define NFH    4     // filters per thread (8 split across fh=0,1)

// ---------------------------------------------------------------------------
// Fully fused kernel: conv1+conv2 (staged in LDS) + conv3 + dense partial dot.
// Grid: (chunk=8, b=64, slice=4). Block: 256 threads.
//   c3loc = tid>>1 (y2 channel within chunk), fh = tid&1 (filter half).
// Thread (c3loc, fh) owns conv3 filters f = fh*4..fh*4+3 of channel
// c3 = chunk*128 + c3loc -> per-thread weights = 24 regs (register-resident,
// unlike R2's 48 which the compiler demoted to per-iter cache reloads).
// W float4 index for (t, c3, fh): t*4096 + c3*4 + fh*2 -> lane i reads 2i+q,
// the two loads jointly cover a contiguous 2KB per wave.
// blockIdx.x = chunk keeps each chunk's 950 KB W-slice pinned to one XCD L2.
// ---------------------------------------------------------------------------
__global__ __launch_bounds__(256, 8) void actor_fused_kernel(
    const float* __restrict__ state,   // [64][128][16]
    const float* __restrict__ k1,      // [5][1][128]
    const float* __restrict__ b1,      // [128]
    const float* __restrict__ k2,      // [5][1][1024]
    const float* __restrict__ b2,      // [1024]
    const float* __restrict__ k3,      // [5][1][8192]
    const float* __restrict__ b3,      // [8192]
    const float* __restrict__ W,       // [950272][2]
    float* __restrict__ partials)      // [64][8][4][2]
{
    const int chunk = blockIdx.x;      // 0..7
    const int b     = blockIdx.y;      // 0..63
    const int slice = blockIdx.z;      // 0..3
    const int t0    = slice * SLICE;   // global t3 offset
    const int tid   = threadIdx.x;     // 0..255
    const int c3loc = tid >> 1;        // 0..127
    const int fh    = tid & 1;         // 0..1
    const int c3    = chunk * 128 + c3loc;

    __shared__ float s_state[STR][2];   // 41 x 2
    __shared__ float s_y1[Y1R][16];     // 37 x 16
    __shared__ float tile[TROWS][128];  // 33 x 128 — y2 slice (16.9 KB)

    // ---- stage state rows [t0, t0+41), this chunk's 2 channels ----
    if (tid < STR * 2) {
        int r = tid >> 1, c = tid & 1;
        s_state[r][c] = state[(size_t)b * L0 * C0 + (t0 + r) * C0 + chunk * 2 + c];
    }
    __syncthreads();

    // ---- block1: y1 rows [t0, t0+37), 16 channels of this chunk ----
    for (int idx = tid; idx < Y1R * 16; idx += 256) {
        int r = idx >> 4, jloc = idx & 15;
        int j = chunk * 16 + jloc;
        int cloc = jloc >> 3;
        float acc = b1[j];
#pragma unroll
        for (int k = 0; k < KW; ++k)
            acc = fmaf(s_state[r + k][cloc], k1[k * CH1 + j], acc);
        s_y1[r][jloc] = fmaxf(acc, 0.f);
    }
    __syncthreads();

    // ---- block2: y2 rows [t0, t0+33); column tid&127, row-half tid>>7 ----
    {
        int c = tid & 127, h = tid >> 7;
        int m = chunk * 128 + c;
        int jloc = c >> 3;
        float kk[KW], bb = b2[m];
#pragma unroll
        for (int k = 0; k < KW; ++k) kk[k] = k2[k * CH2 + m];
        int r0 = h ? 17 : 0, r1 = h ? TROWS : 17;
        for (int r = r0; r < r1; ++r) {
            float acc = bb;
#pragma unroll
            for (int k = 0; k < KW; ++k)
                acc = fmaf(s_y1[r + k][jloc], kk[k], acc);
            tile[r][c] = fmaxf(acc, 0.f);
        }
    }

    // ---- conv3 weights + bias for this thread's 4 filters ----
    float kw[KW][NFH], bv[NFH];
#pragma unroll
    for (int k = 0; k < KW; ++k)
#pragma unroll
        for (int f = 0; f < NFH; ++f)
            kw[k][f] = k3[k * CH3 + c3 * NF + fh * NFH + f];
#pragma unroll
    for (int f = 0; f < NFH; ++f)
        bv[f] = b3[c3 * NF + fh * NFH + f];

    __syncthreads();   // tile ready

    // ---- main loop: conv3 + relu + dense partial dot ----
    float a0x = 0.f, a0y = 0.f, a1x = 0.f, a1y = 0.f;

    const float4* __restrict__ wp =
        (const float4*)W + (size_t)t0 * 4096 + (size_t)c3 * 4 + fh * 2;

    // rolling 5-row window of own y2 column (broadcast pair-reads)
    float w0 = tile[0][c3loc];
    float w1 = tile[1][c3loc];
    float w2 = tile[2][c3loc];
    float w3 = tile[3][c3loc];

    for (int t = 0; t < SLICE; ++t) {
        float w4 = tile[t + 4][c3loc];

        float v[NFH];
#pragma unroll
        for (int f = 0; f < NFH; ++f) {
            float a = bv[f];
            a = fmaf(w0, kw[0][f], a);
            a = fmaf(w1, kw[1][f], a);
            a = fmaf(w2, kw[2][f], a);
            a = fmaf(w3, kw[3][f], a);
            a = fmaf(w4, kw[4][f], a);
            v[f] = fmaxf(a, 0.f);
        }

        float4 q0 = wp[0];   // filters fh*4+0, fh*4+1 (cols x,y / z,w)
        float4 q1 = wp[1];   // filters fh*4+2, fh*4+3
        wp += 4096;

        a0x = fmaf(v[0], q0.x, a0x); a0y = fmaf(v[0], q0.y, a0y);
        a0x = fmaf(v[1], q0.z, a0x); a0y = fmaf(v[1], q0.w, a0y);
        a1x = fmaf(v[2], q1.x, a1x); a1y = fmaf(v[2], q1.y, a1y);
        a1x = fmaf(v[3], q1.z, a1x); a1y = fmaf(v[3], q1.w, a1y);

        w0 = w1; w1 = w2; w2 = w3; w3 = w4;
    }

    float acc0 = a0x + a1x;
    float acc1 = a0y + a1y;

    // wave (64-lane) butterfly reduction, then cross-wave combine
#pragma unroll
    for (int d = 32; d >= 1; d >>= 1) {
        acc0 += __shfl_down(acc0, d, 64);
        acc1 += __shfl_down(acc1, d, 64);
    }
    __shared__ float red[4][2];
    int wave = tid >> 6, lane = tid & 63;
    if (lane == 0) { red[wave][0] = acc0; red[wave][1] = acc1; }
    __syncthreads();
    if (tid == 0) {
        size_t o = (((size_t)b * NCHUNK + chunk) * NS + slice) * 2;
        partials[o + 0] = (red[0][0] + red[1][0]) + (red[2][0] + red[3][0]);
        partials[o + 1] = (red[0][1] + red[1][1]) + (red[2][1] + red[3][1]);
    }
}

// ---------------------------------------------------------------------------
// Combine 32 partials per (b, a), add dense bias, tanh.
// ---------------------------------------------------------------------------
__global__ __launch_bounds__(128) void finish_kernel(
    const float* __restrict__ partials,  // [64][8][4][2] = [64][32][2]
    const float* __restrict__ bd,        // [2]
    float* __restrict__ out)             // [64][2]
{
    int i = threadIdx.x;                 // 0..127
    int b = i >> 1, a = i & 1;
    float s = bd[a];
#pragma unroll
    for (int p = 0; p < NCHUNK * NS; ++p)
        s += partials[((size_t)b * NCHUNK * NS + p) * 2 + a];
    out[b * 2 + a] = tanhf(s);
}

extern "C" void kernel_launch(void* const* d_in, const int* in_sizes, int n_in,
                              void* d_out, int out_size, void* d_ws, size_t ws_size,
                              hipStream_t stream) {
    const float* state = (const float*)d_in[0];
    const float* k1    = (const float*)d_in[1];
    const float* b1    = (const float*)d_in[2];
    const float* k2    = (const float*)d_in[3];
    const float* b2    = (const float*)d_in[4];
    const float* k3    = (const float*)d_in[5];
    const float* b3    = (const float*)d_in[6];
    const float* W     = (const float*)d_in[7];
    const float* bd    = (const float*)d_in[8];
    float* out = (float*)d_out;

    float* partials = (float*)d_ws;   // 64*8*4*2 fp32 = 16 KB

    dim3 grid(NCHUNK, NB, NS);
    actor_fused_kernel<<<grid, 256, 0, stream>>>(
        state, k1, b1, k2, b2, k3, b3, W, partials);

    finish_kernel<<<1, 128, 0, stream>>>(partials, bd, out);
}

// Round 4
// 93.065 us; speedup vs baseline: 1.3694x; 1.0572x over previous
//
#include <hip/hip_runtime.h>
#include <math.h>

// Problem constants
#define NB    64     // batch
#define L0    128    // input length
#define C0    16     // input channels
#define KW    5      // conv kernel size
#define NF    8      // filters per group
#define L1    124
#define L2    120
#define L3    116
#define CH1   128
#define CH2   1024
#define CH3   8192
#define NCHUNK 8     // channel chunks: 2 state ch -> 16 y1 ch -> 128 y2 ch -> 1024 y3 ch
#define NS     4     // time slices of block-3 output
#define SLICE  29    // L3 / NS
#define TROWS  (SLICE + 4)    // y2 rows per slice    = 33
#define Y1R    (SLICE + 8)    // y1 rows per slice    = 37
#define STR    (SLICE + 12)   // state rows per slice = 41
#define NFH    4     // conv3 filters per thread (8 split across fh=0,1)
#define NBATCH 4     // batches per block (batch-blocking: 4x arithmetic per W load)
#define NBG    (NB / NBATCH)  // 16 batch groups

// ---------------------------------------------------------------------------
// Fused conv1+conv2+conv3+dense, batch-blocked x4.
// Grid: (chunk=8, bgroup=16, slice=4) = 512 blocks, 2 blocks/CU.
// Block: 256 threads; c3loc = tid>>1, fh = tid&1 (filter half).
// Rationale vs R3: instead of 8 thin waves/SIMD (which forced a 64-VGPR cap
// and spilled the weights), use 2 fat waves/SIMD with 4 batches of work per
// W load -> ~230 VALU cycles between issuing the two W float4 loads and
// consuming them, hiding L2 latency via ILP. W logical traffic drops 4x
// (486->121 MB; ~3.5 us/XCD L2 floor). ~90 live VGPRs, budget 256: resident.
// blockIdx.x = chunk pins each 950 KB W-slice to one XCD's L2.
// ---------------------------------------------------------------------------
__global__ __launch_bounds__(256, 2) void actor_fused_kernel(
    const float* __restrict__ state,   // [64][128][16]
    const float* __restrict__ k1,      // [5][1][128]
    const float* __restrict__ b1,      // [128]
    const float* __restrict__ k2,      // [5][1][1024]
    const float* __restrict__ b2,      // [1024]
    const float* __restrict__ k3,      // [5][1][8192]
    const float* __restrict__ b3,      // [8192]
    const float* __restrict__ W,       // [950272][2]
    float* __restrict__ partials)      // [64][8][4][2]
{
    const int chunk = blockIdx.x;      // 0..7
    const int bg    = blockIdx.y;      // 0..15
    const int slice = blockIdx.z;      // 0..3
    const int t0    = slice * SLICE;
    const int tid   = threadIdx.x;     // 0..255
    const int c3loc = tid >> 1;        // 0..127
    const int fh    = tid & 1;         // 0..1
    const int c3    = chunk * 128 + c3loc;

    __shared__ float s_state[NBATCH][STR][2];    // 1.3 KB
    __shared__ float s_y1[NBATCH][Y1R][16];      // 9.3 KB
    __shared__ float tile[NBATCH][TROWS][128];   // 66 KB — y2 slices

    // ---- stage state: lane-group bb = tid>>6 loads batch bg*4+bb ----
    {
        int bb = tid >> 6, lt = tid & 63;
        const float* sp = state + (size_t)(bg * NBATCH + bb) * L0 * C0
                        + (size_t)t0 * C0 + chunk * 2;
        for (int i = lt; i < STR * 2; i += 64) {
            int r = i >> 1, c = i & 1;
            s_state[bb][r][c] = sp[r * C0 + c];
        }
    }
    __syncthreads();

    // ---- block1: y1 rows [0,37) x 16 ch, per lane-group batch ----
    {
        int bb = tid >> 6, lt = tid & 63;
        for (int i = lt; i < Y1R * 16; i += 64) {
            int r = i >> 4, jloc = i & 15;
            int j = chunk * 16 + jloc;
            int cloc = jloc >> 3;
            float acc = b1[j];
#pragma unroll
            for (int k = 0; k < KW; ++k)
                acc = fmaf(s_state[bb][r + k][cloc], k1[k * CH1 + j], acc);
            s_y1[bb][r][jloc] = fmaxf(acc, 0.f);
        }
    }
    __syncthreads();

    // ---- block2: column c = tid&127, row-half h = tid>>7, all 4 batches ----
    {
        int c = tid & 127, h = tid >> 7;
        int m = chunk * 128 + c;
        int jloc = c >> 3;
        float kk[KW], b2v = b2[m];
#pragma unroll
        for (int k = 0; k < KW; ++k) kk[k] = k2[k * CH2 + m];
        int r0 = h ? 17 : 0, r1 = h ? TROWS : 17;
#pragma unroll
        for (int bb = 0; bb < NBATCH; ++bb)
            for (int r = r0; r < r1; ++r) {
                float acc = b2v;
#pragma unroll
                for (int k = 0; k < KW; ++k)
                    acc = fmaf(s_y1[bb][r + k][jloc], kk[k], acc);
                tile[bb][r][c] = fmaxf(acc, 0.f);
            }
    }

    // ---- conv3 weights + bias for this thread's 4 filters (registers) ----
    float kw[KW][NFH], bv[NFH];
#pragma unroll
    for (int k = 0; k < KW; ++k)
#pragma unroll
        for (int f = 0; f < NFH; ++f)
            kw[k][f] = k3[k * CH3 + c3 * NF + fh * NFH + f];
#pragma unroll
    for (int f = 0; f < NFH; ++f)
        bv[f] = b3[c3 * NF + fh * NFH + f];

    __syncthreads();   // tiles ready

    // ---- main loop: conv3 + relu + dense partial dot, 4 batches ----
    float ax[NBATCH], ay[NBATCH];
#pragma unroll
    for (int bb = 0; bb < NBATCH; ++bb) { ax[bb] = 0.f; ay[bb] = 0.f; }

    // rolling 4-tap window per batch (5th tap read per iter)
    float w[NBATCH][4];
#pragma unroll
    for (int bb = 0; bb < NBATCH; ++bb)
#pragma unroll
        for (int r = 0; r < 4; ++r)
            w[bb][r] = tile[bb][r][c3loc];

    const float4* __restrict__ wp =
        (const float4*)W + (size_t)t0 * 4096 + (size_t)c3 * 4 + fh * 2;

    for (int t = 0; t < SLICE; ++t) {
        // issue W loads first; ~112 VALU of conv3 below hides their latency
        float4 q0 = wp[0];
        float4 q1 = wp[1];
        wp += 4096;

        float v[NBATCH][NFH];
#pragma unroll
        for (int bb = 0; bb < NBATCH; ++bb) {
            float w4 = tile[bb][t + 4][c3loc];
#pragma unroll
            for (int f = 0; f < NFH; ++f) {
                float a = bv[f];
                a = fmaf(w[bb][0], kw[0][f], a);
                a = fmaf(w[bb][1], kw[1][f], a);
                a = fmaf(w[bb][2], kw[2][f], a);
                a = fmaf(w[bb][3], kw[3][f], a);
                a = fmaf(w4,       kw[4][f], a);
                v[bb][f] = fmaxf(a, 0.f);
            }
            w[bb][0] = w[bb][1]; w[bb][1] = w[bb][2];
            w[bb][2] = w[bb][3]; w[bb][3] = w4;
        }

#pragma unroll
        for (int bb = 0; bb < NBATCH; ++bb) {
            ax[bb] = fmaf(v[bb][0], q0.x, ax[bb]); ay[bb] = fmaf(v[bb][0], q0.y, ay[bb]);
            ax[bb] = fmaf(v[bb][1], q0.z, ax[bb]); ay[bb] = fmaf(v[bb][1], q0.w, ay[bb]);
            ax[bb] = fmaf(v[bb][2], q1.x, ax[bb]); ay[bb] = fmaf(v[bb][2], q1.y, ay[bb]);
            ax[bb] = fmaf(v[bb][3], q1.z, ax[bb]); ay[bb] = fmaf(v[bb][3], q1.w, ay[bb]);
        }
    }

    // ---- wave butterfly reduction per batch, then cross-wave combine ----
#pragma unroll
    for (int bb = 0; bb < NBATCH; ++bb) {
#pragma unroll
        for (int d = 32; d >= 1; d >>= 1) {
            ax[bb] += __shfl_down(ax[bb], d, 64);
            ay[bb] += __shfl_down(ay[bb], d, 64);
        }
    }
    __shared__ float red[4][NBATCH][2];
    int wave = tid >> 6, lane = tid & 63;
    if (lane == 0) {
#pragma unroll
        for (int bb = 0; bb < NBATCH; ++bb) {
            red[wave][bb][0] = ax[bb];
            red[wave][bb][1] = ay[bb];
        }
    }
    __syncthreads();
    if (tid < NBATCH * 2) {
        int bb = tid >> 1, a = tid & 1;
        float s = (red[0][bb][a] + red[1][bb][a]) + (red[2][bb][a] + red[3][bb][a]);
        int b = bg * NBATCH + bb;
        partials[(((size_t)b * NCHUNK + chunk) * NS + slice) * 2 + a] = s;
    }
}

// ---------------------------------------------------------------------------
// Combine 32 partials per (b, a), add dense bias, tanh.
// ---------------------------------------------------------------------------
__global__ __launch_bounds__(128) void finish_kernel(
    const float* __restrict__ partials,  // [64][8][4][2]
    const float* __restrict__ bd,        // [2]
    float* __restrict__ out)             // [64][2]
{
    int i = threadIdx.x;                 // 0..127
    int b = i >> 1, a = i & 1;
    float s = bd[a];
#pragma unroll
    for (int p = 0; p < NCHUNK * NS; ++p)
        s += partials[((size_t)b * NCHUNK * NS + p) * 2 + a];
    out[b * 2 + a] = tanhf(s);
}

extern "C" void kernel_launch(void* const* d_in, const int* in_sizes, int n_in,
                              void* d_out, int out_size, void* d_ws, size_t ws_size,
                              hipStream_t stream) {
    const float* state = (const float*)d_in[0];
    const float* k1    = (const float*)d_in[1];
    const float* b1    = (const float*)d_in[2];
    const float* k2    = (const float*)d_in[3];
    const float* b2    = (const float*)d_in[4];
    const float* k3    = (const float*)d_in[5];
    const float* b3    = (const float*)d_in[6];
    const float* W     = (const float*)d_in[7];
    const float* bd    = (const float*)d_in[8];
    float* out = (float*)d_out;

    float* partials = (float*)d_ws;   // 64*8*4*2 fp32 = 16 KB

    dim3 grid(NCHUNK, NBG, NS);
    actor_fused_kernel<<<grid, 256, 0, stream>>>(
        state, k1, b1, k2, b2, k3, b3, W, partials);

    finish_kernel<<<1, 128, 0, stream>>>(partials, bd, out);
}

// Round 5
// 92.713 us; speedup vs baseline: 1.3746x; 1.0038x over previous
//
#include <hip/hip_runtime.h>
#include <math.h>

// Problem constants
#define NB    64     // batch
#define L0    128    // input length
#define C0    16     // input channels
#define KW    5      // conv kernel size
#define NF    8      // filters per group
#define CH1   128
#define CH2   1024
#define CH3   8192
#define NCHUNK 8     // channel chunks: 2 state ch -> 16 y1 ch -> 128 y2 ch -> 1024 y3 ch
#define NS     4     // time slices of block-3 output
#define SLICE  29    // L3 / NS
#define TROWS  (SLICE + 4)    // y2 rows per slice    = 33
#define Y1R    (SLICE + 8)    // y1 rows per slice    = 37
#define STR    (SLICE + 12)   // state rows per slice = 41
#define NFH    4     // conv3 filters per thread (8 split across fh=0,1)
#define NBATCH 4     // batches per block
#define NBG    (NB / NBATCH)  // 16 batch groups

__device__ __forceinline__ float4 fma4(float4 a, float s, float4 c) {
    return make_float4(fmaf(a.x, s, c.x), fmaf(a.y, s, c.y),
                       fmaf(a.z, s, c.z), fmaf(a.w, s, c.w));
}
__device__ __forceinline__ float4 relu4(float4 a) {
    return make_float4(fmaxf(a.x, 0.f), fmaxf(a.y, 0.f),
                       fmaxf(a.z, 0.f), fmaxf(a.w, 0.f));
}
__device__ __forceinline__ float4 splat4(float s) { return make_float4(s, s, s, s); }

// ---------------------------------------------------------------------------
// Fused conv1+conv2+conv3+dense, batch-blocked x4, batch-INNERMOST LDS layout.
// Grid: (chunk=8, bgroup=16, slice=4) = 512 blocks, 2 blocks/CU, 2 waves/SIMD.
// vs R4: tile/s_y1 are float4 over batches -> main loop does ONE ds_read_b128
// per iter instead of 4 ds_read_b32 (4x less LDS-pipe pressure); conv2 does
// 1 b128 read + 1 b128 write per row via a rolling window (was ~6 b32/row);
// W is software-pipelined one iteration ahead (full-iteration latency cover).
// blockIdx.x = chunk pins each 950 KB W-slice to one XCD's L2 (linear%8).
// ---------------------------------------------------------------------------
__global__ __launch_bounds__(256, 2) void actor_fused_kernel(
    const float* __restrict__ state,   // [64][128][16]
    const float* __restrict__ k1,      // [5][1][128]
    const float* __restrict__ b1,      // [128]
    const float* __restrict__ k2,      // [5][1][1024]
    const float* __restrict__ b2,      // [1024]
    const float* __restrict__ k3,      // [5][1][8192]
    const float* __restrict__ b3,      // [8192]
    const float* __restrict__ W,       // [950272][2]
    float* __restrict__ partials)      // [64][8][4][2]
{
    const int chunk = blockIdx.x;      // 0..7
    const int bg    = blockIdx.y;      // 0..15
    const int slice = blockIdx.z;      // 0..3
    const int t0    = slice * SLICE;
    const int tid   = threadIdx.x;     // 0..255
    const int c3loc = tid >> 1;        // 0..127
    const int fh    = tid & 1;         // 0..1
    const int c3    = chunk * 128 + c3loc;

    __shared__ float  s_state[NBATCH][STR][2];  // 1.3 KB
    __shared__ float4 s_y1[Y1R][16];            // [row][jloc].{x..w}=batch, 9.3 KB
    __shared__ float4 tile[TROWS][128];         // [row][col].{x..w}=batch, 66 KB

    // ---- stage state: lane-group bb = tid>>6 loads batch bg*4+bb ----
    {
        int bb = tid >> 6, lt = tid & 63;
        const float* sp = state + (size_t)(bg * NBATCH + bb) * L0 * C0
                        + (size_t)t0 * C0 + chunk * 2;
        for (int i = lt; i < STR * 2; i += 64) {
            int r = i >> 1, c = i & 1;
            s_state[bb][r][c] = sp[r * C0 + c];
        }
    }
    __syncthreads();

    // ---- conv1: write component bb of s_y1[r][jloc] ----
    {
        int bb = tid >> 6, lt = tid & 63;
        for (int i = lt; i < Y1R * 16; i += 64) {
            int r = i >> 4, jloc = i & 15;
            int j = chunk * 16 + jloc;
            int cloc = jloc >> 3;
            float acc = b1[j];
#pragma unroll
            for (int k = 0; k < KW; ++k)
                acc = fmaf(s_state[bb][r + k][cloc], k1[k * CH1 + j], acc);
            ((float*)&s_y1[r][jloc])[bb] = fmaxf(acc, 0.f);
        }
    }
    __syncthreads();

    // ---- conv2: column c = tid&127, row-half h = tid>>7, all batches via f4 ----
    {
        int c = tid & 127, h = tid >> 7;
        int m = chunk * 128 + c;
        int jloc = c >> 3;
        float kk[KW], b2v = b2[m];
#pragma unroll
        for (int k = 0; k < KW; ++k) kk[k] = k2[k * CH2 + m];
        int r0 = h ? 17 : 0, r1 = h ? TROWS : 17;
        float4 u0 = s_y1[r0 + 0][jloc];
        float4 u1 = s_y1[r0 + 1][jloc];
        float4 u2 = s_y1[r0 + 2][jloc];
        float4 u3 = s_y1[r0 + 3][jloc];
        for (int r = r0; r < r1; ++r) {
            float4 u4 = s_y1[r + 4][jloc];
            float4 acc = splat4(b2v);
            acc = fma4(u0, kk[0], acc);
            acc = fma4(u1, kk[1], acc);
            acc = fma4(u2, kk[2], acc);
            acc = fma4(u3, kk[3], acc);
            acc = fma4(u4, kk[4], acc);
            tile[r][c] = relu4(acc);
            u0 = u1; u1 = u2; u2 = u3; u3 = u4;
        }
    }

    // ---- conv3 weights + bias for this thread's 4 filters (registers) ----
    float kw[KW][NFH], bv[NFH];
#pragma unroll
    for (int k = 0; k < KW; ++k)
#pragma unroll
        for (int f = 0; f < NFH; ++f)
            kw[k][f] = k3[k * CH3 + c3 * NF + fh * NFH + f];
#pragma unroll
    for (int f = 0; f < NFH; ++f)
        bv[f] = b3[c3 * NF + fh * NFH + f];

    __syncthreads();   // tile ready (written by other threads)

    // ---- main loop: conv3 + relu + dense, batch-vectorized float4 ----
    float4 axv = splat4(0.f), ayv = splat4(0.f);

    const float4* __restrict__ wq =
        (const float4*)W + (size_t)t0 * 4096 + (size_t)c3 * 4 + fh * 2;
    float4 cq0 = wq[0];          // W for iteration t (pipelined)
    float4 cq1 = wq[1];

    float4 tw0 = tile[0][c3loc];
    float4 tw1 = tile[1][c3loc];
    float4 tw2 = tile[2][c3loc];
    float4 tw3 = tile[3][c3loc];

    for (int t = 0; t < SLICE; ++t) {
        float4 tw4 = tile[t + 4][c3loc];            // single b128 LDS read
        // prefetch W for t+1 (clamped re-read on last iter; L1-hot, no OOB)
        int tp = (t < SLICE - 1) ? (t + 1) : (SLICE - 1);
        float4 nq0 = wq[(size_t)tp * 4096];
        float4 nq1 = wq[(size_t)tp * 4096 + 1];

        float4 v[NFH];
#pragma unroll
        for (int f = 0; f < NFH; ++f) {
            float4 a = splat4(bv[f]);
            a = fma4(tw0, kw[0][f], a);
            a = fma4(tw1, kw[1][f], a);
            a = fma4(tw2, kw[2][f], a);
            a = fma4(tw3, kw[3][f], a);
            a = fma4(tw4, kw[4][f], a);
            v[f] = relu4(a);
        }

        axv = fma4(v[0], cq0.x, axv); ayv = fma4(v[0], cq0.y, ayv);
        axv = fma4(v[1], cq0.z, axv); ayv = fma4(v[1], cq0.w, ayv);
        axv = fma4(v[2], cq1.x, axv); ayv = fma4(v[2], cq1.y, ayv);
        axv = fma4(v[3], cq1.z, axv); ayv = fma4(v[3], cq1.w, ayv);

        cq0 = nq0; cq1 = nq1;
        tw0 = tw1; tw1 = tw2; tw2 = tw3; tw3 = tw4;
    }

    // ---- wave butterfly reduction (per batch component), cross-wave combine ----
#pragma unroll
    for (int d = 32; d >= 1; d >>= 1) {
        axv.x += __shfl_down(axv.x, d, 64); ayv.x += __shfl_down(ayv.x, d, 64);
        axv.y += __shfl_down(axv.y, d, 64); ayv.y += __shfl_down(ayv.y, d, 64);
        axv.z += __shfl_down(axv.z, d, 64); ayv.z += __shfl_down(ayv.z, d, 64);
        axv.w += __shfl_down(axv.w, d, 64); ayv.w += __shfl_down(ayv.w, d, 64);
    }
    __shared__ float red[4][NBATCH][2];
    int wave = tid >> 6, lane = tid & 63;
    if (lane == 0) {
        red[wave][0][0] = axv.x; red[wave][0][1] = ayv.x;
        red[wave][1][0] = axv.y; red[wave][1][1] = ayv.y;
        red[wave][2][0] = axv.z; red[wave][2][1] = ayv.z;
        red[wave][3][0] = axv.w; red[wave][3][1] = ayv.w;
    }
    __syncthreads();
    if (tid < NBATCH * 2) {
        int bb = tid >> 1, a = tid & 1;
        float s = (red[0][bb][a] + red[1][bb][a]) + (red[2][bb][a] + red[3][bb][a]);
        int b = bg * NBATCH + bb;
        partials[(((size_t)b * NCHUNK + chunk) * NS + slice) * 2 + a] = s;
    }
}

// ---------------------------------------------------------------------------
// Combine 32 partials per (b, a), add dense bias, tanh.
// ---------------------------------------------------------------------------
__global__ __launch_bounds__(128) void finish_kernel(
    const float* __restrict__ partials,  // [64][8][4][2]
    const float* __restrict__ bd,        // [2]
    float* __restrict__ out)             // [64][2]
{
    int i = threadIdx.x;                 // 0..127
    int b = i >> 1, a = i & 1;
    float s = bd[a];
#pragma unroll
    for (int p = 0; p < NCHUNK * NS; ++p)
        s += partials[((size_t)b * NCHUNK * NS + p) * 2 + a];
    out[b * 2 + a] = tanhf(s);
}

extern "C" void kernel_launch(void* const* d_in, const int* in_sizes, int n_in,
                              void* d_out, int out_size, void* d_ws, size_t ws_size,
                              hipStream_t stream) {
    const float* state = (const float*)d_in[0];
    const float* k1    = (const float*)d_in[1];
    const float* b1    = (const float*)d_in[2];
    const float* k2    = (const float*)d_in[3];
    const float* b2    = (const float*)d_in[4];
    const float* k3    = (const float*)d_in[5];
    const float* b3    = (const float*)d_in[6];
    const float* W     = (const float*)d_in[7];
    const float* bd    = (const float*)d_in[8];
    float* out = (float*)d_out;

    float* partials = (float*)d_ws;   // 64*8*4*2 fp32 = 16 KB

    dim3 grid(NCHUNK, NBG, NS);
    actor_fused_kernel<<<grid, 256, 0, stream>>>(
        state, k1, b1, k2, b2, k3, b3, W, partials);

    finish_kernel<<<1, 128, 0, stream>>>(partials, bd, out);
}